// Round 2
// baseline (340.970 us; speedup 1.0000x reference)
//
#include <hip/hip_runtime.h>
#include <math.h>

// ---- problem constants -------------------------------------------------
#define BB   4      // batch
#define NN   128    // sites
#define NPP  16     // pores
#define EEE  1280   // ss edges
#define ESP  1024   // sp/ps edges
#define DD   32     // node feat dim
#define CC   16     // gaussian centers / edge feat dim
#define OO   32     // message dim
#define FIN  80     // 2*DD + CC
#define MMM  64     // head hidden
#define TT   3      // message passing steps

#define GRID 256    // <= 256 CUs -> all blocks co-resident by capacity
#define TPB  256

// ---- workspace layout (floats) ----------------------------------------
constexpr int OFF_S    = 0;
constexpr int OFF_SP   = OFF_S    + BB*NN*DD;      // 16384
constexpr int OFF_BE   = OFF_SP   + BB*NPP*DD;     // 18432
constexpr int OFF_BSP  = OFF_BE   + BB*EEE*CC;     // 100352
constexpr int OFF_BPS  = OFF_BSP  + BB*ESP*CC;     // 165888
constexpr int OFF_MSS  = OFF_BPS  + BB*ESP*CC;     // 231424
constexpr int OFF_MPS  = OFF_MSS  + TT*BB*NN*OO;   // 280576
constexpr int OFF_MSP  = OFF_MPS  + TT*BB*NN*OO;   // 329728
constexpr int OFF_MEND = OFF_MSP  + TT*BB*NPP*OO;  // 335872
constexpr int ZM       = OFF_MEND - OFF_MSS;       // zeroed message region
// node projections (overwritten each step)
constexpr int OFF_SASS = OFF_MEND;                 // s  @ Wa_ss   [B*N*O]
constexpr int OFF_SBSS = OFF_SASS + BB*NN*OO;      // s  @ Wb_ss
constexpr int OFF_SBPS = OFF_SBSS + BB*NN*OO;      // s  @ Wb_ps
constexpr int OFF_SASP = OFF_SBPS + BB*NN*OO;      // s  @ Wa_sp
constexpr int OFF_PAPS = OFF_SASP + BB*NN*OO;      // sp @ Wa_ps   [B*Np*O]
constexpr int OFF_PBSP = OFF_PAPS + BB*NPP*OO;     // sp @ Wb_sp
constexpr int WS_TOTAL = OFF_PBSP + BB*NPP*OO;     // 405504 floats

// ---- grid barrier region (ints, after floats; 128B-aligned) ------------
constexpr int BAR_SLOT_STRIDE = 576;   // ints per slot (counters on own lines)
constexpr int BAR_SLOTS = 7;
constexpr int BAR_BYTES = BAR_SLOTS * BAR_SLOT_STRIDE * 4;

__device__ __forceinline__ float lrelu(float x) { return x > 0.f ? x : 0.01f * x; }

__device__ __forceinline__ void edge_embed(float d, const float* W, const float* bvec, float* out) {
    float g[CC];
#pragma unroll
    for (int c = 0; c < CC; ++c) {
        float mu = (10.0f / 15.0f) * (float)c;  // linspace(0,10,16)
        float z = d - mu;
        g[c] = expf(-z * z);
    }
#pragma unroll
    for (int j = 0; j < CC; ++j) {
        float a = bvec[j];
#pragma unroll
        for (int c = 0; c < CC; ++c) a += g[c] * W[c * CC + j];
        out[j] = lrelu(a);
    }
}

// two-level grid barrier: 16 groups x (GRID/16); AGENT scope + fences.
__device__ __forceinline__ void gbar(int* bar, int slot) {
    __syncthreads();   // drains this block's vmem (stores in L2 before fence)
    if (threadIdx.x == 0) {
        int* base = bar + slot * BAR_SLOT_STRIDE;
        __threadfence();                      // release (L2 writeback, device scope)
        const int g   = (int)blockIdx.x & 15;
        const int nin = GRID >> 4;
        int p = __hip_atomic_fetch_add(base + g * 32, 1, __ATOMIC_ACQ_REL, __HIP_MEMORY_SCOPE_AGENT);
        if (p == nin - 1) {
            int q = __hip_atomic_fetch_add(base + 512, 1, __ATOMIC_ACQ_REL, __HIP_MEMORY_SCOPE_AGENT);
            if (q == 15)
                __hip_atomic_store(base + 544, 1, __ATOMIC_RELEASE, __HIP_MEMORY_SCOPE_AGENT);
        }
        while (__hip_atomic_load(base + 544, __ATOMIC_ACQUIRE, __HIP_MEMORY_SCOPE_AGENT) == 0)
            __builtin_amdgcn_s_sleep(2);
        __threadfence();                      // acquire (cache invalidate)
    }
    __syncthreads();
}

__global__ __launch_bounds__(TPB, 1) void k_fused(
    const float* sites, const float* bonds, const float* sites_p,
    const float* bonds_sp, const float* bonds_ps,
    const int* idx1, const int* idx2, const int* idx1_sp, const int* idx2_sp,
    const int* idx1_ps, const int* idx2_ps,
    const float* se_W, const float* se_b, const float* sep_W, const float* sep_b,
    const float* ee_W, const float* ee_b, const float* eep_W, const float* eep_b,
    const float* eqW1_ss, const float* eqW2_ss, const float* eqb_ss, const float* aw_ss, const float* ab_ss,
    const float* eqW1_ps, const float* eqW2_ps, const float* eqb_ps, const float* aw_ps, const float* ab_ps,
    const float* eqW1_sp, const float* eqW2_sp, const float* eqb_sp, const float* aw_sp, const float* ab_sp,
    const float* nuW1, const float* nub1, const float* nuW2, const float* nub2,
    const float* nupW1, const float* nupb1, const float* nupW2, const float* nupb2,
    const float* p1W, const float* p1b, const float* p2aW, const float* p2ab,
    const float* p2bW, const float* p2bb, const float* p3W, const float* p3b,
    float* ws, float* out, int* bar)
{
    __shared__ float smem[6656];
    const int blk = blockIdx.x;
    const int tid = threadIdx.x;

    // ================= INIT part A: zero messages + edge-feat embeds ====
    {
        const int totalA = ZM + BB*EEE + BB*ESP + BB*ESP;
        for (int i = blk*TPB + tid; i < totalA; i += GRID*TPB) {
            int r = i;
            if (r < ZM) { ws[OFF_MSS + r] = 0.f; continue; }
            r -= ZM;
            if (r < BB*EEE) { edge_embed(bonds[r],    ee_W,  ee_b,  ws + OFF_BE  + r*CC); continue; }
            r -= BB*EEE;
            if (r < BB*ESP) { edge_embed(bonds_sp[r], eep_W, eep_b, ws + OFF_BSP + r*CC); continue; }
            r -= BB*ESP;
            edge_embed(bonds_ps[r], eep_W, eep_b, ws + OFF_BPS + r*CC);
        }
    }
    // ======== INIT part B: node embeddings + t=0 projections ============
    // 72 units of 8 nodes: recompute embedding locally (no intra-phase dep)
    for (int u = blk; u < 72; u += GRID) {
        const int el = tid >> 5, o = tid & 31;
        float* sP   = smem;            // up to 4096 floats of proj weights
        float* sRow = smem + 4160;     // 8 x 32 node rows
        if (u < 64) {                  // sites
            const int g = u*8 + el;    // flat b*NN + n
            float x = sites[g];
            float v0 = lrelu(x * se_W[o] + se_b[o]);
            ws[OFF_S + g*DD + o] = v0;
            sRow[el*32 + o] = v0;
            for (int i2 = tid; i2 < 4096; i2 += TPB) {
                int m = i2 >> 10, j = i2 & 1023, d = j >> 5, oo = j & 31;
                int row = (m == 1 || m == 2) ? (32 + d) : d;   // Wa_ss,Wb_ss,Wb_ps,Wa_sp
                float wv;
                if (m < 2)      wv = eqW1_ss[row*OO + oo] + eqW2_ss[row*OO + oo];
                else if (m==2)  wv = eqW1_ps[row*OO + oo] + eqW2_ps[row*OO + oo];
                else            wv = eqW1_sp[row*OO + oo] + eqW2_sp[row*OO + oo];
                sP[i2] = wv;
            }
            __syncthreads();
            float p0=0.f,p1=0.f,p2=0.f,p3=0.f;
#pragma unroll
            for (int d = 0; d < 32; ++d) {
                float sv = sRow[el*32 + d];
                p0 += sv * sP[        d*32 + o];
                p1 += sv * sP[1024 +  d*32 + o];
                p2 += sv * sP[2048 +  d*32 + o];
                p3 += sv * sP[3072 +  d*32 + o];
            }
            ws[OFF_SASS + g*OO + o] = p0;
            ws[OFF_SBSS + g*OO + o] = p1;
            ws[OFF_SBPS + g*OO + o] = p2;
            ws[OFF_SASP + g*OO + o] = p3;
        } else {                       // pores
            const int g = (u-64)*8 + el;   // flat b*NPP + p
            float x0 = sites_p[g*2], x1 = sites_p[g*2+1];
            float v0 = lrelu(x0 * sep_W[o] + x1 * sep_W[DD + o] + sep_b[o]);
            ws[OFF_SP + g*DD + o] = v0;
            sRow[el*32 + o] = v0;
            for (int i2 = tid; i2 < 2048; i2 += TPB) {
                int m = i2 >> 10, j = i2 & 1023, d = j >> 5, oo = j & 31;
                int row = (m == 0) ? d : (32 + d);             // Wa_ps, Wb_sp
                float wv;
                if (m == 0) wv = eqW1_ps[row*OO + oo] + eqW2_ps[row*OO + oo];
                else        wv = eqW1_sp[row*OO + oo] + eqW2_sp[row*OO + oo];
                sP[i2] = wv;
            }
            __syncthreads();
            float p0=0.f,p1=0.f;
#pragma unroll
            for (int d = 0; d < 32; ++d) {
                float sv = sRow[el*32 + d];
                p0 += sv * sP[        d*32 + o];
                p1 += sv * sP[1024 +  d*32 + o];
            }
            ws[OFF_PAPS + g*OO + o] = p0;
            ws[OFF_PBSP + g*OO + o] = p1;
        }
    }
    gbar(bar, 0);

    for (int t = 0; t < TT; ++t) {
        // ============== EDGE phase: pure per-lane, no LDS/sync ==========
        {
            const int i0 = blk*TPB + tid;
            const int o  = i0 & 31;                 // fixed per thread
            float we[CC]; float bias_o = 0.f, aw_o = 0.f, ab_s = 0.f;
            int curst = -1;
            for (int i = i0; i < 13312*32; i += GRID*TPB) {
                const int erow = i >> 5;
                int st, e, b; const int *iaP, *ibP;
                const float *SAb, *SBb, *ef; float* mb;
                if (erow < BB*EEE) {
                    st = 0; b = erow / EEE; e = erow - b*EEE;
                    iaP = idx1; ibP = idx2;
                    SAb = ws + OFF_SASS + b*(NN*OO);
                    SBb = ws + OFF_SBSS + b*(NN*OO);
                    ef  = ws + OFF_BE + erow*CC;
                    mb  = ws + OFF_MSS + t*(BB*NN*OO) + b*(NN*OO);
                } else if (erow < BB*EEE + BB*ESP) {
                    int rr = erow - BB*EEE; st = 1; b = rr >> 10; e = rr & (ESP-1);
                    iaP = idx1_ps; ibP = idx2_ps;
                    SAb = ws + OFF_PAPS + b*(NPP*OO);
                    SBb = ws + OFF_SBPS + b*(NN*OO);
                    ef  = ws + OFF_BPS + rr*CC;
                    mb  = ws + OFF_MPS + t*(BB*NN*OO) + b*(NN*OO);
                } else {
                    int rr = erow - (BB*EEE + BB*ESP); st = 2; b = rr >> 10; e = rr & (ESP-1);
                    iaP = idx1_sp; ibP = idx2_sp;
                    SAb = ws + OFF_SASP + b*(NN*OO);
                    SBb = ws + OFF_PBSP + b*(NPP*OO);
                    ef  = ws + OFF_BSP + rr*CC;
                    mb  = ws + OFF_MSP + t*(BB*NPP*OO) + b*(NPP*OO);
                }
                if (st != curst) {
                    const float *w1p, *w2p, *bp, *awp, *abp;
                    if (st == 0) { w1p=eqW1_ss; w2p=eqW2_ss; bp=eqb_ss; awp=aw_ss; abp=ab_ss; }
                    else if (st == 1) { w1p=eqW1_ps; w2p=eqW2_ps; bp=eqb_ps; awp=aw_ps; abp=ab_ps; }
                    else { w1p=eqW1_sp; w2p=eqW2_sp; bp=eqb_sp; awp=aw_sp; abp=ab_sp; }
                    const float* wa = w1p + t*(FIN*OO) + 2*DD*OO + o;
                    const float* wb = w2p + t*(FIN*OO) + 2*DD*OO + o;
#pragma unroll
                    for (int c = 0; c < CC; ++c) we[c] = wa[c*OO] + wb[c*OO];
                    bias_o = bp[t*OO + o]; aw_o = awp[t*OO + o]; ab_s = abp[t];
                    curst = st;
                }
                const int s1 = iaP[e], s2 = ibP[e];
                float acc = bias_o + SAb[s1*OO + o] + SBb[s2*OO + o];
#pragma unroll
                for (int c = 0; c < CC; ++c) acc += ef[c] * we[c];
                float uu = lrelu(acc);
                float rr2 = uu * aw_o;
#pragma unroll
                for (int mm = 16; mm > 0; mm >>= 1) rr2 += __shfl_xor(rr2, mm, 32);
                float gate = 1.f / (1.f + expf(-(rr2 + ab_s)));
                atomicAdd(&mb[s2*OO + o], gate * uu);
            }
        }
        gbar(bar, 1 + 2*t);

        // ============== NODE phase: update + next-step projections ======
        for (int u = blk; u < 72; u += GRID) {
            float* sW1 = smem;          // 96x32
            float* sW2 = smem + 3072;   // 32x32
            float* sb1 = smem + 4096;
            float* sb2 = smem + 4128;
            float* sh  = smem + 4160;   // 8x96
            float* su  = smem + 4928;   // 8x32
            const float* mss = ws + OFF_MSS + t*(BB*NN*OO);
            const float* mps = ws + OFF_MPS + t*(BB*NN*OO);
            const float* msp = ws + OFF_MSP + t*(BB*NPP*OO);
            const int el = tid >> 5, o = tid & 31;
            if (u < 64) {               // sites
                const float* W1 = nuW1 + t*96*32;
                const float* W2 = nuW2 + t*32*32;
                for (int i = tid; i < 96*32; i += TPB) sW1[i] = W1[i];
                for (int i = tid; i < 32*32; i += TPB) sW2[i] = W2[i];
                if (tid < 32) { sb1[tid] = nub1[t*32 + tid]; sb2[tid] = nub2[t*32 + tid]; }
                for (int i = tid; i < 8*96; i += TPB) {
                    int e2 = i / 96, f = i - e2*96;
                    int g = u*8 + e2;
                    float v;
                    if (f < 32)      v = ws[OFF_S + g*DD + f];
                    else if (f < 64) v = mss[g*OO + (f-32)];
                    else             v = mps[g*OO + (f-64)];
                    sh[i] = v;
                }
                __syncthreads();
                float acc = sb1[o];
#pragma unroll
                for (int f = 0; f < 96; ++f) acc += sh[el*96 + f] * sW1[f*32 + o];
                su[el*32 + o] = lrelu(acc);
                __syncthreads();
                float acc2 = sb2[o];
#pragma unroll
                for (int k = 0; k < 32; ++k) acc2 += su[el*32 + k] * sW2[k*32 + o];
                const int g = u*8 + el;
                float snew = sh[el*96 + o] + lrelu(acc2);
                __syncthreads();                 // all reads of sW*/su/sh done
                ws[OFF_S + g*DD + o] = snew;
                float* sRow = smem + 4928;       // reuse su
                sRow[el*32 + o] = snew;
                if (t < TT-1) {
                    const int tn = t + 1;
                    float* sP = smem;            // overwrite sW1/sW2
                    for (int i2 = tid; i2 < 4096; i2 += TPB) {
                        int m = i2 >> 10, j = i2 & 1023, d = j >> 5, oo = j & 31;
                        int row = (m == 1 || m == 2) ? (32 + d) : d;
                        float wv;
                        if (m < 2)     wv = eqW1_ss[tn*FIN*OO + row*OO + oo] + eqW2_ss[tn*FIN*OO + row*OO + oo];
                        else if (m==2) wv = eqW1_ps[tn*FIN*OO + row*OO + oo] + eqW2_ps[tn*FIN*OO + row*OO + oo];
                        else           wv = eqW1_sp[tn*FIN*OO + row*OO + oo] + eqW2_sp[tn*FIN*OO + row*OO + oo];
                        sP[i2] = wv;
                    }
                    __syncthreads();
                    float p0=0.f,p1=0.f,p2=0.f,p3=0.f;
#pragma unroll
                    for (int d = 0; d < 32; ++d) {
                        float sv = sRow[el*32 + d];
                        p0 += sv * sP[        d*32 + o];
                        p1 += sv * sP[1024 +  d*32 + o];
                        p2 += sv * sP[2048 +  d*32 + o];
                        p3 += sv * sP[3072 +  d*32 + o];
                    }
                    ws[OFF_SASS + g*OO + o] = p0;
                    ws[OFF_SBSS + g*OO + o] = p1;
                    ws[OFF_SBPS + g*OO + o] = p2;
                    ws[OFF_SASP + g*OO + o] = p3;
                }
            } else {                    // pores
                const int u2 = u - 64;
                const float* W1 = nupW1 + t*64*32;
                const float* W2 = nupW2 + t*32*32;
                for (int i = tid; i < 64*32; i += TPB) sW1[i] = W1[i];
                for (int i = tid; i < 32*32; i += TPB) sW2[i] = W2[i];
                if (tid < 32) { sb1[tid] = nupb1[t*32 + tid]; sb2[tid] = nupb2[t*32 + tid]; }
                for (int i = tid; i < 8*64; i += TPB) {
                    int e2 = i >> 6, f = i & 63;
                    int g = u2*8 + e2;
                    float v;
                    if (f < 32) v = ws[OFF_SP + g*DD + f];
                    else        v = msp[g*OO + (f-32)];
                    sh[i] = v;
                }
                __syncthreads();
                float acc = sb1[o];
#pragma unroll
                for (int f = 0; f < 64; ++f) acc += sh[el*64 + f] * sW1[f*32 + o];
                su[el*32 + o] = lrelu(acc);
                __syncthreads();
                float acc2 = sb2[o];
#pragma unroll
                for (int k = 0; k < 32; ++k) acc2 += su[el*32 + k] * sW2[k*32 + o];
                const int g = u2*8 + el;
                float snew = sh[el*64 + o] + lrelu(acc2);
                __syncthreads();
                ws[OFF_SP + g*DD + o] = snew;
                float* sRow = smem + 4928;
                sRow[el*32 + o] = snew;
                if (t < TT-1) {
                    const int tn = t + 1;
                    float* sP = smem;
                    for (int i2 = tid; i2 < 2048; i2 += TPB) {
                        int m = i2 >> 10, j = i2 & 1023, d = j >> 5, oo = j & 31;
                        int row = (m == 0) ? d : (32 + d);
                        float wv;
                        if (m == 0) wv = eqW1_ps[tn*FIN*OO + row*OO + oo] + eqW2_ps[tn*FIN*OO + row*OO + oo];
                        else        wv = eqW1_sp[tn*FIN*OO + row*OO + oo] + eqW2_sp[tn*FIN*OO + row*OO + oo];
                        sP[i2] = wv;
                    }
                    __syncthreads();
                    float p0=0.f,p1=0.f;
#pragma unroll
                    for (int d = 0; d < 32; ++d) {
                        float sv = sRow[el*32 + d];
                        p0 += sv * sP[        d*32 + o];
                        p1 += sv * sP[1024 +  d*32 + o];
                    }
                    ws[OFF_PAPS + g*OO + o] = p0;
                    ws[OFF_PBSP + g*OO + o] = p1;
                }
            }
        }
        gbar(bar, 2 + 2*t);
    }

    // ================= HEAD: pooling + MLP, blocks 0..3 =================
    if (blk < BB) {
        float* sS   = smem;            // 128x32
        float* sWh  = smem + 4096;     // 32x64
        float* part = smem + 6144;     // 4x64
        float* xv   = smem + 6400;
        float* yv   = smem + 6464;
        float* zv   = smem + 6528;
        const float* s = ws + OFF_S + blk*NN*DD;
        for (int i = tid; i < NN*DD; i += TPB) sS[i] = s[i];
        for (int i = tid; i < DD*MMM; i += TPB) sWh[i] = p1W[i];
        __syncthreads();
        const int m = tid & 63, q = tid >> 6;
        float accp = 0.f;
        for (int n = q*32; n < q*32 + 32; ++n) {
            float a = p1b[m];
#pragma unroll
            for (int d = 0; d < DD; ++d) a += sS[n*DD + d] * sWh[d*MMM + m];
            accp += lrelu(a);
        }
        part[q*64 + m] = accp;
        __syncthreads();
        if (tid < MMM) xv[tid] = part[tid] + part[64 + tid] + part[128 + tid] + part[192 + tid];
        __syncthreads();
        if (tid < MMM) {
            float a = p2ab[tid];
#pragma unroll
            for (int k = 0; k < MMM; ++k) a += xv[k] * p2aW[k*MMM + tid];
            yv[tid] = lrelu(a);
        }
        __syncthreads();
        if (tid < MMM) {
            float a = p2bb[tid];
#pragma unroll
            for (int k = 0; k < MMM; ++k) a += yv[k] * p2bW[k*MMM + tid];
            zv[tid] = lrelu(a);
        }
        __syncthreads();
        if (tid == 0) {
            float a = p3b[0];
#pragma unroll
            for (int k = 0; k < MMM; ++k) a += zv[k] * p3W[k];
            out[blk] = a;
        }
    }
}

// ---- launch ------------------------------------------------------------
extern "C" void kernel_launch(void* const* d_in, const int* in_sizes, int n_in,
                              void* d_out, int out_size, void* d_ws, size_t ws_size,
                              hipStream_t stream) {
    (void)in_sizes; (void)n_in; (void)out_size; (void)ws_size;
    const float* sites    = (const float*)d_in[0];
    const float* bonds    = (const float*)d_in[1];
    const float* sites_p  = (const float*)d_in[2];
    const float* bonds_sp = (const float*)d_in[3];
    const float* bonds_ps = (const float*)d_in[4];
    const int* idx1    = (const int*)d_in[5];
    const int* idx2    = (const int*)d_in[6];
    const int* idx1_sp = (const int*)d_in[7];
    const int* idx2_sp = (const int*)d_in[8];
    const int* idx1_ps = (const int*)d_in[9];
    const int* idx2_ps = (const int*)d_in[10];
    const float* se_W  = (const float*)d_in[11];
    const float* se_b  = (const float*)d_in[12];
    const float* sep_W = (const float*)d_in[13];
    const float* sep_b = (const float*)d_in[14];
    const float* ee_W  = (const float*)d_in[15];
    const float* ee_b  = (const float*)d_in[16];
    const float* eep_W = (const float*)d_in[17];
    const float* eep_b = (const float*)d_in[18];
    const float* eqW1_ss = (const float*)d_in[19];
    const float* eqW2_ss = (const float*)d_in[20];
    const float* eqb_ss  = (const float*)d_in[21];
    const float* aw_ss   = (const float*)d_in[22];
    const float* ab_ss   = (const float*)d_in[23];
    const float* eqW1_ps = (const float*)d_in[24];
    const float* eqW2_ps = (const float*)d_in[25];
    const float* eqb_ps  = (const float*)d_in[26];
    const float* aw_ps   = (const float*)d_in[27];
    const float* ab_ps   = (const float*)d_in[28];
    const float* eqW1_sp = (const float*)d_in[29];
    const float* eqW2_sp = (const float*)d_in[30];
    const float* eqb_sp  = (const float*)d_in[31];
    const float* aw_sp   = (const float*)d_in[32];
    const float* ab_sp   = (const float*)d_in[33];
    const float* nuW1  = (const float*)d_in[34];
    const float* nub1  = (const float*)d_in[35];
    const float* nuW2  = (const float*)d_in[36];
    const float* nub2  = (const float*)d_in[37];
    const float* nupW1 = (const float*)d_in[38];
    const float* nupb1 = (const float*)d_in[39];
    const float* nupW2 = (const float*)d_in[40];
    const float* nupb2 = (const float*)d_in[41];
    const float* p1W  = (const float*)d_in[42];
    const float* p1b  = (const float*)d_in[43];
    const float* p2aW = (const float*)d_in[44];
    const float* p2ab = (const float*)d_in[45];
    const float* p2bW = (const float*)d_in[46];
    const float* p2bb = (const float*)d_in[47];
    const float* p3W  = (const float*)d_in[48];
    const float* p3b  = (const float*)d_in[49];

    float* ws  = (float*)d_ws;
    float* out = (float*)d_out;
    int*   bar = (int*)((char*)d_ws + (size_t)WS_TOTAL * 4);

    hipMemsetAsync(bar, 0, BAR_BYTES, stream);
    k_fused<<<GRID, TPB, 0, stream>>>(
        sites, bonds, sites_p, bonds_sp, bonds_ps,
        idx1, idx2, idx1_sp, idx2_sp, idx1_ps, idx2_ps,
        se_W, se_b, sep_W, sep_b, ee_W, ee_b, eep_W, eep_b,
        eqW1_ss, eqW2_ss, eqb_ss, aw_ss, ab_ss,
        eqW1_ps, eqW2_ps, eqb_ps, aw_ps, ab_ps,
        eqW1_sp, eqW2_sp, eqb_sp, aw_sp, ab_sp,
        nuW1, nub1, nuW2, nub2, nupW1, nupb1, nupW2, nupb2,
        p1W, p1b, p2aW, p2ab, p2bW, p2bb, p3W, p3b,
        ws, out, bar);
}

// Round 3
// 59.989 us; speedup vs baseline: 5.6839x; 5.6839x over previous
//
#include <hip/hip_runtime.h>
#include <math.h>

// ---- problem constants -------------------------------------------------
#define BB   4      // batch
#define NN   128    // sites
#define NPP  16     // pores
#define EEE  1280   // ss edges
#define ESP  1024   // sp/ps edges
#define DD   32     // node feat dim
#define CC   16     // gaussian centers / edge feat dim
#define OO   32     // message dim
#define FIN  80     // 2*DD + CC
#define MMM  64     // head hidden
#define TT   3      // message passing steps
#define TPB  256

// ---- workspace layout (floats) ----------------------------------------
constexpr int OFF_S    = 0;
constexpr int OFF_SP   = OFF_S    + BB*NN*DD;      // 16384
constexpr int OFF_BE   = OFF_SP   + BB*NPP*DD;     // 18432
constexpr int OFF_BSP  = OFF_BE   + BB*EEE*CC;     // 100352
constexpr int OFF_BPS  = OFF_BSP  + BB*ESP*CC;     // 165888
constexpr int OFF_MSS  = OFF_BPS  + BB*ESP*CC;     // 231424
constexpr int OFF_MPS  = OFF_MSS  + TT*BB*NN*OO;   // 280576
constexpr int OFF_MSP  = OFF_MPS  + TT*BB*NN*OO;   // 329728
constexpr int OFF_MEND = OFF_MSP  + TT*BB*NPP*OO;  // 335872
constexpr int ZM       = OFF_MEND - OFF_MSS;       // zeroed message region
// per-node projections through the equivariant weights (refreshed each step)
constexpr int OFF_SASS = OFF_MEND;                 // s  @ Wa_ss   [B*N*O]
constexpr int OFF_SBSS = OFF_SASS + BB*NN*OO;      // s  @ Wb_ss
constexpr int OFF_SBPS = OFF_SBSS + BB*NN*OO;      // s  @ Wb_ps
constexpr int OFF_SASP = OFF_SBPS + BB*NN*OO;      // s  @ Wa_sp
constexpr int OFF_PAPS = OFF_SASP + BB*NN*OO;      // sp @ Wa_ps   [B*Np*O]
constexpr int OFF_PBSP = OFF_PAPS + BB*NPP*OO;     // sp @ Wb_sp
constexpr int WS_TOTAL = OFF_PBSP + BB*NPP*OO;     // 405504 floats

__device__ __forceinline__ float lrelu(float x) { return x > 0.f ? x : 0.01f * x; }

__device__ __forceinline__ void edge_embed(float d, const float* W, const float* bvec, float* out) {
    float g[CC];
#pragma unroll
    for (int c = 0; c < CC; ++c) {
        float mu = (10.0f / 15.0f) * (float)c;  // linspace(0,10,16)
        float z = d - mu;                        // WIDTH = 1.0
        g[c] = expf(-z * z);
    }
#pragma unroll
    for (int j = 0; j < CC; ++j) {
        float a = bvec[j];
#pragma unroll
        for (int c = 0; c < CC; ++c) a += g[c] * W[c * CC + j];
        out[j] = lrelu(a);
    }
}

// ---- K0: zero messages + edge embeds + node embeds + t=0 projections ---
__global__ __launch_bounds__(TPB) void k_init(
    const float* sites, const float* bonds, const float* sites_p,
    const float* bonds_sp, const float* bonds_ps,
    const float* se_W, const float* se_b, const float* sep_W, const float* sep_b,
    const float* ee_W, const float* ee_b, const float* eep_W, const float* eep_b,
    const float* eqW1_ss, const float* eqW2_ss,
    const float* eqW1_ps, const float* eqW2_ps,
    const float* eqW1_sp, const float* eqW2_sp,
    float* ws)
{
    __shared__ float smem[4416];     // sP[4096] + sRow[256]
    const int blk = blockIdx.x;
    const int tid = threadIdx.x;

    // part A: zero message buffers + edge-feature embeddings (grid-stride)
    {
        const int totalA = ZM + BB*EEE + BB*ESP + BB*ESP;
        for (int i = blk*TPB + tid; i < totalA; i += gridDim.x*TPB) {
            int r = i;
            if (r < ZM) { ws[OFF_MSS + r] = 0.f; continue; }
            r -= ZM;
            if (r < BB*EEE) { edge_embed(bonds[r],    ee_W,  ee_b,  ws + OFF_BE  + r*CC); continue; }
            r -= BB*EEE;
            if (r < BB*ESP) { edge_embed(bonds_sp[r], eep_W, eep_b, ws + OFF_BSP + r*CC); continue; }
            r -= BB*ESP;
            edge_embed(bonds_ps[r], eep_W, eep_b, ws + OFF_BPS + r*CC);
        }
    }
    // part B: node embeddings + t=0 projections (blocks 0..71, 8 nodes each)
    if (blk < 72) {
        const int el = tid >> 5, o = tid & 31;
        float* sP   = smem;            // projection weights
        float* sRow = smem + 4160;     // 8 x 32 node rows
        if (blk < 64) {                // sites
            const int g = blk*8 + el;  // flat b*NN + n
            float x = sites[g];
            float v0 = lrelu(x * se_W[o] + se_b[o]);
            ws[OFF_S + g*DD + o] = v0;
            sRow[el*32 + o] = v0;
            for (int i2 = tid; i2 < 4096; i2 += TPB) {
                int m = i2 >> 10, j = i2 & 1023, d = j >> 5, oo = j & 31;
                int row = (m == 1 || m == 2) ? (32 + d) : d;   // Wa_ss,Wb_ss,Wb_ps,Wa_sp
                float wv;
                if (m < 2)      wv = eqW1_ss[row*OO + oo] + eqW2_ss[row*OO + oo];
                else if (m==2)  wv = eqW1_ps[row*OO + oo] + eqW2_ps[row*OO + oo];
                else            wv = eqW1_sp[row*OO + oo] + eqW2_sp[row*OO + oo];
                sP[i2] = wv;
            }
            __syncthreads();
            float p0=0.f,p1=0.f,p2=0.f,p3=0.f;
#pragma unroll
            for (int d = 0; d < 32; ++d) {
                float sv = sRow[el*32 + d];
                p0 += sv * sP[        d*32 + o];
                p1 += sv * sP[1024 +  d*32 + o];
                p2 += sv * sP[2048 +  d*32 + o];
                p3 += sv * sP[3072 +  d*32 + o];
            }
            ws[OFF_SASS + g*OO + o] = p0;
            ws[OFF_SBSS + g*OO + o] = p1;
            ws[OFF_SBPS + g*OO + o] = p2;
            ws[OFF_SASP + g*OO + o] = p3;
        } else {                       // pores
            const int g = (blk-64)*8 + el;   // flat b*NPP + p
            float x0 = sites_p[g*2], x1 = sites_p[g*2+1];
            float v0 = lrelu(x0 * sep_W[o] + x1 * sep_W[DD + o] + sep_b[o]);
            ws[OFF_SP + g*DD + o] = v0;
            sRow[el*32 + o] = v0;
            for (int i2 = tid; i2 < 2048; i2 += TPB) {
                int m = i2 >> 10, j = i2 & 1023, d = j >> 5, oo = j & 31;
                int row = (m == 0) ? d : (32 + d);             // Wa_ps, Wb_sp
                float wv;
                if (m == 0) wv = eqW1_ps[row*OO + oo] + eqW2_ps[row*OO + oo];
                else        wv = eqW1_sp[row*OO + oo] + eqW2_sp[row*OO + oo];
                sP[i2] = wv;
            }
            __syncthreads();
            float p0=0.f,p1=0.f;
#pragma unroll
            for (int d = 0; d < 32; ++d) {
                float sv = sRow[el*32 + d];
                p0 += sv * sP[        d*32 + o];
                p1 += sv * sP[1024 +  d*32 + o];
            }
            ws[OFF_PAPS + g*OO + o] = p0;
            ws[OFF_PBSP + g*OO + o] = p1;
        }
    }
}

// ---- K1: edge phase, projection-split ----------------------------------
// grid = 1664 blocks x 256 threads; thread = (edge, o); block = 8 edges,
// all in the same stream. u = lrelu(SA[s1]+SB[s2]+ef.We+b); gate = sigmoid;
// atomicAdd m[recv] += gate*u.
__global__ __launch_bounds__(TPB) void k_edges(
    const float* eqW1_ss, const float* eqW2_ss, const float* eqb_ss, const float* aw_ss, const float* ab_ss,
    const float* eqW1_ps, const float* eqW2_ps, const float* eqb_ps, const float* aw_ps, const float* ab_ps,
    const float* eqW1_sp, const float* eqW2_sp, const float* eqb_sp, const float* aw_sp, const float* ab_sp,
    const int* idx1, const int* idx2, const int* idx1_sp, const int* idx2_sp,
    const int* idx1_ps, const int* idx2_ps,
    float* ws, int t)
{
    __shared__ float sWe[CC*OO];   // edge-feature rows of W1+W2 (16x32)
    __shared__ float sB[OO], sAw[OO];
    __shared__ float sAb;

    const int tid = threadIdx.x;
    const int blk = blockIdx.x;
    const int el = tid >> 5, o = tid & 31;

    constexpr int NB_SS = BB*EEE/8;   // 640
    constexpr int NB_PS = BB*ESP/8;   // 512

    const float *w1p, *w2p, *bp, *awp, *abp;
    const float *SAb, *SBb, *ef; float* mb;
    int s1, s2;

    if (blk < NB_SS) {                 // ss
        const int rloc = blk*8 + el;
        const int b = rloc / EEE, e = rloc - b*EEE;
        s1 = idx1[e]; s2 = idx2[e];
        SAb = ws + OFF_SASS + b*(NN*OO);
        SBb = ws + OFF_SBSS + b*(NN*OO);
        ef  = ws + OFF_BE  + rloc*CC;
        mb  = ws + OFF_MSS + t*(BB*NN*OO) + b*(NN*OO);
        w1p = eqW1_ss; w2p = eqW2_ss; bp = eqb_ss; awp = aw_ss; abp = ab_ss;
    } else if (blk < NB_SS + NB_PS) {  // ps
        const int rloc = (blk - NB_SS)*8 + el;
        const int b = rloc >> 10, e = rloc & (ESP-1);
        s1 = idx1_ps[e]; s2 = idx2_ps[e];
        SAb = ws + OFF_PAPS + b*(NPP*OO);
        SBb = ws + OFF_SBPS + b*(NN*OO);
        ef  = ws + OFF_BPS + rloc*CC;
        mb  = ws + OFF_MPS + t*(BB*NN*OO) + b*(NN*OO);
        w1p = eqW1_ps; w2p = eqW2_ps; bp = eqb_ps; awp = aw_ps; abp = ab_ps;
    } else {                           // sp
        const int rloc = (blk - NB_SS - NB_PS)*8 + el;
        const int b = rloc >> 10, e = rloc & (ESP-1);
        s1 = idx1_sp[e]; s2 = idx2_sp[e];
        SAb = ws + OFF_SASP + b*(NN*OO);
        SBb = ws + OFF_PBSP + b*(NPP*OO);
        ef  = ws + OFF_BSP + rloc*CC;
        mb  = ws + OFF_MSP + t*(BB*NPP*OO) + b*(NPP*OO);
        w1p = eqW1_sp; w2p = eqW2_sp; bp = eqb_sp; awp = aw_sp; abp = ab_sp;
    }

    const float* wa = w1p + t*(FIN*OO) + 2*DD*OO;   // edge-feature rows
    const float* wb = w2p + t*(FIN*OO) + 2*DD*OO;
    for (int i = tid; i < CC*OO; i += TPB) sWe[i] = wa[i] + wb[i];
    if (tid < OO) { sB[tid] = bp[t*OO + tid]; sAw[tid] = awp[t*OO + tid]; }
    if (tid == 0) sAb = abp[t];
    __syncthreads();

    const float4 e0 = *(const float4*)(ef);
    const float4 e1 = *(const float4*)(ef + 4);
    const float4 e2 = *(const float4*)(ef + 8);
    const float4 e3 = *(const float4*)(ef + 12);

    float acc = sB[o] + SAb[s1*OO + o] + SBb[s2*OO + o];
    acc += e0.x*sWe[ 0*32+o] + e0.y*sWe[ 1*32+o] + e0.z*sWe[ 2*32+o] + e0.w*sWe[ 3*32+o];
    acc += e1.x*sWe[ 4*32+o] + e1.y*sWe[ 5*32+o] + e1.z*sWe[ 6*32+o] + e1.w*sWe[ 7*32+o];
    acc += e2.x*sWe[ 8*32+o] + e2.y*sWe[ 9*32+o] + e2.z*sWe[10*32+o] + e2.w*sWe[11*32+o];
    acc += e3.x*sWe[12*32+o] + e3.y*sWe[13*32+o] + e3.z*sWe[14*32+o] + e3.w*sWe[15*32+o];

    float u = lrelu(acc);
    float r = u * sAw[o];
#pragma unroll
    for (int mm = 16; mm > 0; mm >>= 1) r += __shfl_xor(r, mm, 32);
    float gate = 1.f / (1.f + expf(-(r + sAb)));
    atomicAdd(&mb[s2*OO + o], gate * u);
}

// ---- K2: node updates + next-step projections --------------------------
__global__ __launch_bounds__(TPB) void k_nodes(
    const float* nuW1, const float* nub1, const float* nuW2, const float* nub2,
    const float* nupW1, const float* nupb1, const float* nupW2, const float* nupb2,
    const float* eqW1_ss, const float* eqW2_ss,
    const float* eqW1_ps, const float* eqW2_ps,
    const float* eqW1_sp, const float* eqW2_sp,
    float* ws, int t)
{
    __shared__ float smem[5184];
    const int tid = threadIdx.x;
    const int blk = blockIdx.x;
    float* sW1 = smem;          // 96x32
    float* sW2 = smem + 3072;   // 32x32
    float* sb1 = smem + 4096;
    float* sb2 = smem + 4128;
    float* sh  = smem + 4160;   // 8x96
    float* su  = smem + 4928;   // 8x32
    const float* mss = ws + OFF_MSS + t*(BB*NN*OO);
    const float* mps = ws + OFF_MPS + t*(BB*NN*OO);
    const float* msp = ws + OFF_MSP + t*(BB*NPP*OO);
    const int el = tid >> 5, o = tid & 31;

    if (blk < 64) {               // sites: 8 per block; h = [s, m_ss, m_ps]
        const float* W1 = nuW1 + t*96*32;
        const float* W2 = nuW2 + t*32*32;
        for (int i = tid; i < 96*32; i += TPB) sW1[i] = W1[i];
        for (int i = tid; i < 32*32; i += TPB) sW2[i] = W2[i];
        if (tid < 32) { sb1[tid] = nub1[t*32 + tid]; sb2[tid] = nub2[t*32 + tid]; }
        for (int i = tid; i < 8*96; i += TPB) {
            int e2 = i / 96, f = i - e2*96;
            int g = blk*8 + e2;
            float v;
            if (f < 32)      v = ws[OFF_S + g*DD + f];
            else if (f < 64) v = mss[g*OO + (f-32)];
            else             v = mps[g*OO + (f-64)];
            sh[i] = v;
        }
        __syncthreads();
        float acc = sb1[o];
#pragma unroll
        for (int f = 0; f < 96; ++f) acc += sh[el*96 + f] * sW1[f*32 + o];
        su[el*32 + o] = lrelu(acc);
        __syncthreads();
        float acc2 = sb2[o];
#pragma unroll
        for (int k = 0; k < 32; ++k) acc2 += su[el*32 + k] * sW2[k*32 + o];
        const int g = blk*8 + el;
        float snew = sh[el*96 + o] + lrelu(acc2);
        __syncthreads();                 // all reads of sW*/su/sh done
        ws[OFF_S + g*DD + o] = snew;
        float* sRow = smem + 4928;       // reuse su
        sRow[el*32 + o] = snew;
        if (t < TT-1) {
            const int tn = t + 1;
            float* sP = smem;            // overwrite sW1/sW2
            for (int i2 = tid; i2 < 4096; i2 += TPB) {
                int m = i2 >> 10, j = i2 & 1023, d = j >> 5, oo = j & 31;
                int row = (m == 1 || m == 2) ? (32 + d) : d;
                float wv;
                if (m < 2)     wv = eqW1_ss[tn*FIN*OO + row*OO + oo] + eqW2_ss[tn*FIN*OO + row*OO + oo];
                else if (m==2) wv = eqW1_ps[tn*FIN*OO + row*OO + oo] + eqW2_ps[tn*FIN*OO + row*OO + oo];
                else           wv = eqW1_sp[tn*FIN*OO + row*OO + oo] + eqW2_sp[tn*FIN*OO + row*OO + oo];
                sP[i2] = wv;
            }
            __syncthreads();
            float p0=0.f,p1=0.f,p2=0.f,p3=0.f;
#pragma unroll
            for (int d = 0; d < 32; ++d) {
                float sv = sRow[el*32 + d];
                p0 += sv * sP[        d*32 + o];
                p1 += sv * sP[1024 +  d*32 + o];
                p2 += sv * sP[2048 +  d*32 + o];
                p3 += sv * sP[3072 +  d*32 + o];
            }
            ws[OFF_SASS + g*OO + o] = p0;
            ws[OFF_SBSS + g*OO + o] = p1;
            ws[OFF_SBPS + g*OO + o] = p2;
            ws[OFF_SASP + g*OO + o] = p3;
        }
    } else {                    // pores: 8 per block; h = [sp, m_sp]
        const int u2 = blk - 64;
        const float* W1 = nupW1 + t*64*32;
        const float* W2 = nupW2 + t*32*32;
        for (int i = tid; i < 64*32; i += TPB) sW1[i] = W1[i];
        for (int i = tid; i < 32*32; i += TPB) sW2[i] = W2[i];
        if (tid < 32) { sb1[tid] = nupb1[t*32 + tid]; sb2[tid] = nupb2[t*32 + tid]; }
        for (int i = tid; i < 8*64; i += TPB) {
            int e2 = i >> 6, f = i & 63;
            int g = u2*8 + e2;
            float v;
            if (f < 32) v = ws[OFF_SP + g*DD + f];
            else        v = msp[g*OO + (f-32)];
            sh[i] = v;
        }
        __syncthreads();
        float acc = sb1[o];
#pragma unroll
        for (int f = 0; f < 64; ++f) acc += sh[el*64 + f] * sW1[f*32 + o];
        su[el*32 + o] = lrelu(acc);
        __syncthreads();
        float acc2 = sb2[o];
#pragma unroll
        for (int k = 0; k < 32; ++k) acc2 += su[el*32 + k] * sW2[k*32 + o];
        const int g = u2*8 + el;
        float snew = sh[el*64 + o] + lrelu(acc2);
        __syncthreads();
        ws[OFF_SP + g*DD + o] = snew;
        float* sRow = smem + 4928;
        sRow[el*32 + o] = snew;
        if (t < TT-1) {
            const int tn = t + 1;
            float* sP = smem;
            for (int i2 = tid; i2 < 2048; i2 += TPB) {
                int m = i2 >> 10, j = i2 & 1023, d = j >> 5, oo = j & 31;
                int row = (m == 0) ? d : (32 + d);
                float wv;
                if (m == 0) wv = eqW1_ps[tn*FIN*OO + row*OO + oo] + eqW2_ps[tn*FIN*OO + row*OO + oo];
                else        wv = eqW1_sp[tn*FIN*OO + row*OO + oo] + eqW2_sp[tn*FIN*OO + row*OO + oo];
                sP[i2] = wv;
            }
            __syncthreads();
            float p0=0.f,p1=0.f;
#pragma unroll
            for (int d = 0; d < 32; ++d) {
                float sv = sRow[el*32 + d];
                p0 += sv * sP[        d*32 + o];
                p1 += sv * sP[1024 +  d*32 + o];
            }
            ws[OFF_PAPS + g*OO + o] = p0;
            ws[OFF_PBSP + g*OO + o] = p1;
        }
    }
}

// ---- K3: pooling + MLP head (one block per batch) ----------------------
__global__ __launch_bounds__(TPB) void k_head(
    const float* p1W, const float* p1b, const float* p2aW, const float* p2ab,
    const float* p2bW, const float* p2bb, const float* p3W, const float* p3b,
    const float* ws, float* out)
{
    __shared__ float sS[NN * DD];
    __shared__ float sW[DD * MMM];
    __shared__ float part[4][MMM];
    __shared__ float xv[MMM], yv[MMM], zv[MMM];

    const int b = blockIdx.x;
    const int tid = threadIdx.x;
    const float* s = ws + OFF_S + b * NN * DD;

    for (int i = tid; i < NN * DD; i += TPB) sS[i] = s[i];
    for (int i = tid; i < DD * MMM; i += TPB) sW[i] = p1W[i];
    __syncthreads();

    const int m = tid & 63;
    const int q = tid >> 6;
    float accp = 0.f;
    for (int n = q * 32; n < q * 32 + 32; ++n) {
        float a = p1b[m];
#pragma unroll
        for (int d = 0; d < DD; ++d) a += sS[n * DD + d] * sW[d * MMM + m];
        accp += lrelu(a);
    }
    part[q][m] = accp;
    __syncthreads();

    if (tid < MMM) xv[tid] = part[0][tid] + part[1][tid] + part[2][tid] + part[3][tid];
    __syncthreads();
    if (tid < MMM) {
        float a = p2ab[tid];
#pragma unroll
        for (int k = 0; k < MMM; ++k) a += xv[k] * p2aW[k * MMM + tid];
        yv[tid] = lrelu(a);
    }
    __syncthreads();
    if (tid < MMM) {
        float a = p2bb[tid];
#pragma unroll
        for (int k = 0; k < MMM; ++k) a += yv[k] * p2bW[k * MMM + tid];
        zv[tid] = lrelu(a);
    }
    __syncthreads();
    if (tid == 0) {
        float a = p3b[0];
#pragma unroll
        for (int k = 0; k < MMM; ++k) a += zv[k] * p3W[k];
        out[b] = a;
    }
}

// ---- launch ------------------------------------------------------------
extern "C" void kernel_launch(void* const* d_in, const int* in_sizes, int n_in,
                              void* d_out, int out_size, void* d_ws, size_t ws_size,
                              hipStream_t stream) {
    (void)in_sizes; (void)n_in; (void)out_size; (void)ws_size;
    const float* sites    = (const float*)d_in[0];
    const float* bonds    = (const float*)d_in[1];
    const float* sites_p  = (const float*)d_in[2];
    const float* bonds_sp = (const float*)d_in[3];
    const float* bonds_ps = (const float*)d_in[4];
    const int* idx1    = (const int*)d_in[5];
    const int* idx2    = (const int*)d_in[6];
    const int* idx1_sp = (const int*)d_in[7];
    const int* idx2_sp = (const int*)d_in[8];
    const int* idx1_ps = (const int*)d_in[9];
    const int* idx2_ps = (const int*)d_in[10];
    const float* se_W  = (const float*)d_in[11];
    const float* se_b  = (const float*)d_in[12];
    const float* sep_W = (const float*)d_in[13];
    const float* sep_b = (const float*)d_in[14];
    const float* ee_W  = (const float*)d_in[15];
    const float* ee_b  = (const float*)d_in[16];
    const float* eep_W = (const float*)d_in[17];
    const float* eep_b = (const float*)d_in[18];
    const float* eqW1_ss = (const float*)d_in[19];
    const float* eqW2_ss = (const float*)d_in[20];
    const float* eqb_ss  = (const float*)d_in[21];
    const float* aw_ss   = (const float*)d_in[22];
    const float* ab_ss   = (const float*)d_in[23];
    const float* eqW1_ps = (const float*)d_in[24];
    const float* eqW2_ps = (const float*)d_in[25];
    const float* eqb_ps  = (const float*)d_in[26];
    const float* aw_ps   = (const float*)d_in[27];
    const float* ab_ps   = (const float*)d_in[28];
    const float* eqW1_sp = (const float*)d_in[29];
    const float* eqW2_sp = (const float*)d_in[30];
    const float* eqb_sp  = (const float*)d_in[31];
    const float* aw_sp   = (const float*)d_in[32];
    const float* ab_sp   = (const float*)d_in[33];
    const float* nuW1  = (const float*)d_in[34];
    const float* nub1  = (const float*)d_in[35];
    const float* nuW2  = (const float*)d_in[36];
    const float* nub2  = (const float*)d_in[37];
    const float* nupW1 = (const float*)d_in[38];
    const float* nupb1 = (const float*)d_in[39];
    const float* nupW2 = (const float*)d_in[40];
    const float* nupb2 = (const float*)d_in[41];
    const float* p1W  = (const float*)d_in[42];
    const float* p1b  = (const float*)d_in[43];
    const float* p2aW = (const float*)d_in[44];
    const float* p2ab = (const float*)d_in[45];
    const float* p2bW = (const float*)d_in[46];
    const float* p2bb = (const float*)d_in[47];
    const float* p3W  = (const float*)d_in[48];
    const float* p3b  = (const float*)d_in[49];

    float* ws  = (float*)d_ws;
    float* out = (float*)d_out;

    k_init<<<256, TPB, 0, stream>>>(sites, bonds, sites_p, bonds_sp, bonds_ps,
                                    se_W, se_b, sep_W, sep_b, ee_W, ee_b, eep_W, eep_b,
                                    eqW1_ss, eqW2_ss, eqW1_ps, eqW2_ps, eqW1_sp, eqW2_sp, ws);

    const int edge_blocks = BB*EEE/8 + BB*ESP/8 + BB*ESP/8;  // 1664
    for (int t = 0; t < TT; ++t) {
        k_edges<<<edge_blocks, TPB, 0, stream>>>(
            eqW1_ss, eqW2_ss, eqb_ss, aw_ss, ab_ss,
            eqW1_ps, eqW2_ps, eqb_ps, aw_ps, ab_ps,
            eqW1_sp, eqW2_sp, eqb_sp, aw_sp, ab_sp,
            idx1, idx2, idx1_sp, idx2_sp, idx1_ps, idx2_ps, ws, t);
        k_nodes<<<72, TPB, 0, stream>>>(nuW1, nub1, nuW2, nub2,
                                        nupW1, nupb1, nupW2, nupb2,
                                        eqW1_ss, eqW2_ss, eqW1_ps, eqW2_ps, eqW1_sp, eqW2_sp,
                                        ws, t);
    }
    k_head<<<4, TPB, 0, stream>>>(p1W, p1b, p2aW, p2ab, p2bW, p2bb, p3W, p3b, ws, out);
}